// Round 8
// baseline (1482.552 us; speedup 1.0000x reference)
//
#include <hip/hip_runtime.h>

#define EMBED 128
#define NCODE 10000
#define NSAMP 16384
#define NCODE_PAD 10240
#define NSPLIT 8
#define SPLIT_CODES 1280
#define NCHUNK 20                 // chunks per split, 64 codes each
#define CHUNK_ELEMS 8192          // ushorts per chunk (hi-only): 2mb*8ks*2kh*256
#define OUT_ELEMS (NSAMP * EMBED)
#define TAU 0.25f                 // >=7 sigma of asymmetric-split pairwise error

typedef float f32x16 __attribute__((ext_vector_type(16)));
typedef short s16x8 __attribute__((ext_vector_type(8)));
typedef unsigned short ushort_t;
typedef unsigned long long u64;

// ---- ws byte offsets (~9.7 MB) ----
#define OFF_A   0                 // A hi-only bf16, swizzled (2.62 MB)
#define OFF_CT  2621440           // CT fp32 [n][k] (5.24 MB)
#define OFF_CN  7864320           // cnorm fp32 [10240]
#define OFF_KEY 7905280           // candKey u64 [16384][8]
#define OFF_C2  8953856           // cand2 u32 [16384][8]
#define OFF_IDX 9478144
#define OFF_RL  9543680
#define OFF_CNT 9609216

__device__ __forceinline__ unsigned short f2bf(float f) {   // RNE fp32->bf16
    unsigned u = __float_as_uint(f);
    return (unsigned short)((u + 0x7fffu + ((u >> 16) & 1u)) >> 16);
}
__device__ __forceinline__ float bf2f(unsigned short h) {
    return __uint_as_float(((unsigned)h) << 16);
}
__device__ __forceinline__ unsigned ordf(float f) {         // order-preserving fp32->u32
    unsigned u = __float_as_uint(f);
    return (u & 0x80000000u) ? ~u : (u | 0x80000000u);
}
__device__ __forceinline__ float unordf(unsigned o) {
    return __uint_as_float((o & 0x80000000u) ? (o ^ 0x80000000u) : ~o);
}

// ---- prep: cnorm (exact fp32) + zero loss/counter ----
__global__ __launch_bounds__(256) void prep_norm(const float* __restrict__ C,
                                                 float* __restrict__ cnorm,
                                                 float* __restrict__ out,
                                                 int* __restrict__ counter) {
    int j = blockIdx.x * 256 + threadIdx.x;
    if (j == 0) { out[OUT_ELEMS] = 0.f; *counter = 0; }
    if (j >= NCODE_PAD) return;
    if (j >= NCODE) { cnorm[j] = 3.0e38f; return; }
    float s = 0.f;
#pragma unroll 8
    for (int d = 0; d < EMBED; ++d) {
        float v = C[d * NCODE + j];
        s = fmaf(v, v, s);
    }
    cnorm[j] = s;
}

// ---- prep: codes -> hi-only bf16 A-stream (swizzled) + CT fp32 [n][k] ----
// layout: [split][chunk]{ [mb][ks][kh][row32][8] }
__global__ __launch_bounds__(256) void prep_c3(const float* __restrict__ C,
                                               ushort_t* __restrict__ A,
                                               float* __restrict__ CT) {
    int o = blockIdx.x * 256 + threadIdx.x;   // 163840 threads
    int n  = o % NCODE_PAD;
    int kg = o / NCODE_PAD;                   // 0..15
    int split = n / SPLIT_CODES;
    int rem   = n % SPLIT_CODES;
    int chunk = rem >> 6;
    int mb    = (rem >> 5) & 1;
    int row   = rem & 31;
    int ks = kg >> 1, kh = kg & 1;
    size_t eoff = (size_t)(split * NCHUNK + chunk) * CHUNK_ELEMS
                + (size_t)((((mb * 8 + ks) * 2 + kh) * 256) + row * 8);
    int k0 = kg * 8;
    float f[8];
#pragma unroll
    for (int j = 0; j < 8; ++j)
        f[j] = (n < NCODE) ? C[(size_t)(k0 + j) * NCODE + n] : 0.f;
    *(float4*)(CT + (size_t)n * EMBED + k0)     = make_float4(f[0], f[1], f[2], f[3]);
    *(float4*)(CT + (size_t)n * EMBED + k0 + 4) = make_float4(f[4], f[5], f[6], f[7]);
    s16x8 vh;
#pragma unroll
    for (int j = 0; j < 8; ++j) vh[j] = (short)f2bf(f[j]);
    *(s16x8*)(A + eoff) = vh;
}

// ---- main: persistent-X (B, split -2x), hi-only codes (A) via LDS dbuf ----
// d = cnorm[j] (exact, epilogue) + sum a_h*(-2x). Argmin per-lane.
__global__ __launch_bounds__(256, 2) void vq5(const float* __restrict__ X,
                                              const ushort_t* __restrict__ A,
                                              const float* __restrict__ cnorm,
                                              u64* __restrict__ candKey,
                                              unsigned* __restrict__ cand2) {
    __shared__ ushort_t Bs[2 * CHUNK_ELEMS];   // 32 KB dbuf
    const int t    = threadIdx.x;
    const int lane = t & 63;
    const int wave = t >> 6;
    const int ln   = lane & 31;
    const int kh   = lane >> 5;
    const int split = blockIdx.y;
    const int m0    = blockIdx.x * 256;

    // ---- persistent B frags: (-2x) RNE-split hi+lo ----
    s16x8 bh[2][8], bl[2][8];
#pragma unroll
    for (int g = 0; g < 2; ++g) {
        int m = m0 + wave * 64 + g * 32 + ln;
#pragma unroll
        for (int ks = 0; ks < 8; ++ks) {
            const float* src = X + (size_t)m * EMBED + ks * 16 + kh * 8;
            float4 f0 = *(const float4*)src;
            float4 f1 = *(const float4*)(src + 4);
            float f[8] = {f0.x, f0.y, f0.z, f0.w, f1.x, f1.y, f1.z, f1.w};
            s16x8 vh, vl;
#pragma unroll
            for (int j = 0; j < 8; ++j) {
                float v = -2.f * f[j];
                unsigned short h = f2bf(v);
                vh[j] = (short)h;
                vl[j] = (short)f2bf(v - bf2f(h));
            }
            bh[g][ks] = vh;
            bl[g][ks] = vl;
        }
    }

    float v1[2] = {3.4e38f, 3.4e38f}, v2[2] = {3.4e38f, 3.4e38f};
    int   j1[2] = {0, 0};

    auto ldsw = (__attribute__((address_space(3))) ushort_t*)Bs;
    const int wdst = wave * 2048;              // ushort units: 4 KB/wave
    const size_t chbase = (size_t)(split * NCHUNK) * CHUNK_ELEMS;

    // ---- stage chunk 0 into buf 0 ----
    {
        const ushort_t* s = A + chbase + wdst + lane * 8;
#pragma unroll
        for (int i = 0; i < 4; ++i)
            __builtin_amdgcn_global_load_lds(
                (const __attribute__((address_space(1))) void*)(s + i * 512),
                (__attribute__((address_space(3))) void*)(ldsw + wdst + i * 512),
                16, 0, 0);
    }
    __syncthreads();

    for (int c = 0; c < NCHUNK; ++c) {
        const int b = c & 1;
        // ---- prefetch chunk c+1 into the other buffer (async) ----
        if (c + 1 < NCHUNK) {
            const ushort_t* s = A + chbase + (size_t)(c + 1) * CHUNK_ELEMS + wdst + lane * 8;
            const int db = (1 - b) * CHUNK_ELEMS + wdst;
#pragma unroll
            for (int i = 0; i < 4; ++i)
                __builtin_amdgcn_global_load_lds(
                    (const __attribute__((address_space(1))) void*)(s + i * 512),
                    (__attribute__((address_space(3))) void*)(ldsw + db + i * 512),
                    16, 0, 0);
        }

        // ---- compute chunk c: 4 acc chains (mb x g), 64 MFMA, 16 LDS reads ----
        const int bb = b * CHUNK_ELEMS;
        f32x16 acc00 = {0,0,0,0,0,0,0,0,0,0,0,0,0,0,0,0};
        f32x16 acc01 = {0,0,0,0,0,0,0,0,0,0,0,0,0,0,0,0};
        f32x16 acc10 = {0,0,0,0,0,0,0,0,0,0,0,0,0,0,0,0};
        f32x16 acc11 = {0,0,0,0,0,0,0,0,0,0,0,0,0,0,0,0};
#pragma unroll
        for (int ks = 0; ks < 8; ++ks) {
            const int fo0 = bb + ((ks * 2 + kh) * 256) + ln * 8;          // mb=0
            const int fo1 = fo0 + 4096;                                    // mb=1
            s16x8 a0 = *(const s16x8*)&Bs[fo0];
            s16x8 a1 = *(const s16x8*)&Bs[fo1];
            acc00 = __builtin_amdgcn_mfma_f32_32x32x16_bf16(a0, bh[0][ks], acc00, 0, 0, 0);
            acc01 = __builtin_amdgcn_mfma_f32_32x32x16_bf16(a0, bh[1][ks], acc01, 0, 0, 0);
            acc10 = __builtin_amdgcn_mfma_f32_32x32x16_bf16(a1, bh[0][ks], acc10, 0, 0, 0);
            acc11 = __builtin_amdgcn_mfma_f32_32x32x16_bf16(a1, bh[1][ks], acc11, 0, 0, 0);
            acc00 = __builtin_amdgcn_mfma_f32_32x32x16_bf16(a0, bl[0][ks], acc00, 0, 0, 0);
            acc01 = __builtin_amdgcn_mfma_f32_32x32x16_bf16(a0, bl[1][ks], acc01, 0, 0, 0);
            acc10 = __builtin_amdgcn_mfma_f32_32x32x16_bf16(a1, bl[0][ks], acc10, 0, 0, 0);
            acc11 = __builtin_amdgcn_mfma_f32_32x32x16_bf16(a1, bl[1][ks], acc11, 0, 0, 0);
        }

        // ---- epilogue: d = acc + exact cnorm; per-lane top-2 (no shuffles) ----
        const int cbase = split * SPLIT_CODES + c * 64 + 4 * kh;
#pragma unroll
        for (int r = 0; r < 16; ++r) {
            const int off = (r & 3) + 8 * (r >> 2);
            const int code0 = cbase + off;
            const int code1 = code0 + 32;
            const float cn0 = cnorm[code0];   // 256-B window, L1-hot, hw-uniform
            const float cn1 = cnorm[code1];
            float d;
            d = acc00[r] + cn0;
            if (d < v1[0]) { v2[0] = v1[0]; v1[0] = d; j1[0] = code0; }
            else           { v2[0] = fminf(v2[0], d); }
            d = acc10[r] + cn1;
            if (d < v1[0]) { v2[0] = v1[0]; v1[0] = d; j1[0] = code1; }
            else           { v2[0] = fminf(v2[0], d); }
            d = acc01[r] + cn0;
            if (d < v1[1]) { v2[1] = v1[1]; v1[1] = d; j1[1] = code0; }
            else           { v2[1] = fminf(v2[1], d); }
            d = acc11[r] + cn1;
            if (d < v1[1]) { v2[1] = v1[1]; v1[1] = d; j1[1] = code1; }
            else           { v2[1] = fminf(v2[1], d); }
        }
        __syncthreads();   // buf b reads done; prefetch into 1-b drained
    }

    // merge lane^32 (same sample, other code-subset), emit per-split top-2
#pragma unroll
    for (int g = 0; g < 2; ++g) {
        float ov1 = __shfl_xor(v1[g], 32, 64);
        int   oj1 = __shfl_xor(j1[g], 32, 64);
        float ov2 = __shfl_xor(v2[g], 32, 64);
        float hi = fmaxf(v1[g], ov1);
        v2[g] = fminf(fminf(v2[g], ov2), hi);
        if (ov1 < v1[g] || (ov1 == v1[g] && oj1 < j1[g])) { v1[g] = ov1; j1[g] = oj1; }
        if (kh == 0) {
            int m = m0 + wave * 64 + g * 32 + ln;
            candKey[(size_t)m * NSPLIT + split] =
                ((u64)ordf(v1[g]) << 32) | (unsigned)j1[g];
            cand2[(size_t)m * NSPLIT + split] = ordf(v2[g]);
        }
    }
}

// ---- fused finalize + output: merge 8 candidates, flag near-ties, gather, loss ----
__global__ __launch_bounds__(256) void outfin_k(const float* __restrict__ X,
                                                const float* __restrict__ CT,
                                                const u64* __restrict__ candKey,
                                                const unsigned* __restrict__ cand2,
                                                int* __restrict__ idxf,
                                                int* __restrict__ rlist,
                                                int* __restrict__ counter,
                                                float* __restrict__ out) {
    __shared__ float red[4];
    const int t = threadIdx.x;
    const int m = blockIdx.x * 8 + (t >> 5);
    const int l = t & 31;

    int code = 0;
    if (l == 0) {
        u64 best = 0xffffffffffffffffull;
        float v2 = 3.4e38f;
#pragma unroll
        for (int s = 0; s < NSPLIT; ++s) {
            u64 k = candKey[(size_t)m * NSPLIT + s];
            unsigned o2 = cand2[(size_t)m * NSPLIT + s];
            if (k < best) {
                if (best != 0xffffffffffffffffull)
                    v2 = fminf(v2, unordf((unsigned)(best >> 32)));
                best = k;
                v2 = fminf(v2, unordf(o2));
            } else {
                v2 = fminf(v2, unordf((unsigned)(k >> 32)));
            }
        }
        code = (int)(unsigned)(best & 0xffffffffu);
        idxf[m] = code;
        float v1 = unordf((unsigned)(best >> 32));
        if (v2 - v1 <= TAU) rlist[atomicAdd(counter, 1)] = m;
    }
    code = __shfl(code, 0, 32);

    float4 q = *(const float4*)(CT + (size_t)code * EMBED + l * 4);
    float4 x = *(const float4*)(X + (size_t)m * EMBED + l * 4);
    *(float4*)(out + (size_t)m * EMBED + l * 4) = q;
    float dx = q.x - x.x, dy = q.y - x.y, dz = q.z - x.z, dw = q.w - x.w;
    float lsum = dx * dx + dy * dy + dz * dz + dw * dw;
#pragma unroll
    for (int off = 1; off < 64; off <<= 1) lsum += __shfl_xor(lsum, off, 64);
    if ((t & 63) == 0) red[t >> 6] = lsum;
    __syncthreads();
    if (t == 0)
        atomicAdd(out + OUT_ELEMS,
                  (red[0] + red[1] + red[2] + red[3]) * (1.25f / (float)OUT_ELEMS));
}

// ---- rescue: exact fp32 argmin, ONE BLOCK PER FLAGGED SAMPLE, inline patch ----
__global__ __launch_bounds__(256) void rescue_one(const float* __restrict__ X,
                                                  const float* __restrict__ CT,
                                                  const float* __restrict__ cnorm,
                                                  const int* __restrict__ rlist,
                                                  const int* __restrict__ counter,
                                                  const int* __restrict__ idxf,
                                                  float* __restrict__ out) {
    __shared__ float xs[EMBED];
    __shared__ u64 wk[4];
    __shared__ int sjn;
    const int t = threadIdx.x;
    const int lane = t & 63;
    const int wave = t >> 6;
    const int hw = t & 31;       // lane within half-wave
    const int rowoff = t >> 5;   // 0..7
    const int cnt = *counter;

    for (int s = blockIdx.x; s < cnt; s += gridDim.x) {
        const int m = rlist[s];
        __syncthreads();   // previous iteration's xs/wk reads complete
        if (t < 32) {
            float4 v = *(const float4*)(X + (size_t)m * EMBED + t * 4);
            xs[t * 4 + 0] = v.x; xs[t * 4 + 1] = v.y;
            xs[t * 4 + 2] = v.z; xs[t * 4 + 3] = v.w;
        }
        __syncthreads();
        const float x0 = xs[hw * 4 + 0], x1 = xs[hw * 4 + 1];
        const float x2 = xs[hw * 4 + 2], x3 = xs[hw * 4 + 3];
        u64 bk = 0xffffffffffffffffull;
        for (int it = 0; it < 1250; ++it) {
            int row = it * 8 + rowoff;           // covers 0..9999 exactly
            float4 cv = *(const float4*)(CT + (size_t)row * EMBED + hw * 4);
            float part = x0 * cv.x;
            part = fmaf(x1, cv.y, part);
            part = fmaf(x2, cv.z, part);
            part = fmaf(x3, cv.w, part);
#pragma unroll
            for (int off = 1; off < 32; off <<= 1)
                part += __shfl_xor(part, off, 32);
            if (hw == 0) {
                float d = fmaf(-2.f, part, cnorm[row]);
                u64 key = ((u64)ordf(d) << 32) | (unsigned)row;
                if (key < bk) bk = key;
            }
        }
#pragma unroll
        for (int off = 1; off < 64; off <<= 1) {
            u64 o = __shfl_xor(bk, off, 64);
            if (o < bk) bk = o;
        }
        if (lane == 0) wk[wave] = bk;
        __syncthreads();
        if (t == 0) {
            u64 b = wk[0];
            if (wk[1] < b) b = wk[1];
            if (wk[2] < b) b = wk[2];
            if (wk[3] < b) b = wk[3];
            sjn = (int)(unsigned)(b & 0xffffffffu);
        }
        __syncthreads();
        const int jn = sjn;
        const int jo = idxf[m];
        if (jn != jo) {
            if (t < 32) {
                float4 qn = *(const float4*)(CT + (size_t)jn * EMBED + t * 4);
                float4 qo = *(const float4*)(CT + (size_t)jo * EMBED + t * 4);
                float xa = xs[t * 4 + 0], xb = xs[t * 4 + 1];
                float xc = xs[t * 4 + 2], xd = xs[t * 4 + 3];
                *(float4*)(out + (size_t)m * EMBED + t * 4) = qn;
                float dn = (qn.x - xa) * (qn.x - xa) + (qn.y - xb) * (qn.y - xb)
                         + (qn.z - xc) * (qn.z - xc) + (qn.w - xd) * (qn.w - xd);
                float dp = (qo.x - xa) * (qo.x - xa) + (qo.y - xb) * (qo.y - xb)
                         + (qo.z - xc) * (qo.z - xc) + (qo.w - xd) * (qo.w - xd);
                float delta = dn - dp;
#pragma unroll
                for (int off = 1; off < 32; off <<= 1)
                    delta += __shfl_xor(delta, off, 32);
                if (t == 0)
                    atomicAdd(out + OUT_ELEMS, delta * (1.25f / (float)OUT_ELEMS));
            }
        }
    }
}

extern "C" void kernel_launch(void* const* d_in, const int* in_sizes, int n_in,
                              void* d_out, int out_size, void* d_ws, size_t ws_size,
                              hipStream_t stream) {
    const float* X = (const float*)d_in[0];   // (16384,128) fp32
    const float* C = (const float*)d_in[1];   // (128,10000) fp32
    float* out = (float*)d_out;
    char* ws = (char*)d_ws;

    ushort_t* A  = (ushort_t*)(ws + OFF_A);
    float* CT    = (float*)(ws + OFF_CT);
    float* cnorm = (float*)(ws + OFF_CN);
    u64* candKey = (u64*)(ws + OFF_KEY);
    unsigned* cand2 = (unsigned*)(ws + OFF_C2);
    int* idxf    = (int*)(ws + OFF_IDX);
    int* rlist   = (int*)(ws + OFF_RL);
    int* counter = (int*)(ws + OFF_CNT);

    prep_norm<<<NCODE_PAD / 256, 256, 0, stream>>>(C, cnorm, out, counter);
    prep_c3<<<(NCODE_PAD * 16) / 256, 256, 0, stream>>>(C, A, CT);
    vq5<<<dim3(NSAMP / 256, NSPLIT), 256, 0, stream>>>(X, A, cnorm, candKey, cand2);
    outfin_k<<<NSAMP / 8, 256, 0, stream>>>(X, CT, candKey, cand2, idxf, rlist, counter, out);
    rescue_one<<<512, 256, 0, stream>>>(X, CT, cnorm, rlist, counter, idxf, out);
}

// Round 9
// 649.250 us; speedup vs baseline: 2.2835x; 2.2835x over previous
//
#include <hip/hip_runtime.h>

#define EMBED 128
#define NCODE 10000
#define NSAMP 16384
#define NCODE_PAD 10240
#define NSPLIT 8
#define SPLIT_CODES 1280
#define NCHUNK 20                 // chunks per split, 64 codes each
#define CHUNK_ELEMS 8192          // ushorts per chunk per (h|l): 2mb*8ks*2kh*256
#define OUT_ELEMS (NSAMP * EMBED)
#define TAU 0.002f                // ~28 sigma of full split-bf16 pairwise error

typedef float f32x16 __attribute__((ext_vector_type(16)));
typedef short s16x8 __attribute__((ext_vector_type(8)));
typedef unsigned short ushort_t;
typedef unsigned long long u64;

// ---- ws byte offsets (~12.3 MB) ----
#define OFF_AH  0                 // codes hi bf16, swizzled (2.62 MB)
#define OFF_AL  2621440           // codes lo bf16
#define OFF_CT  5242880           // CT fp32 [n][k] (5.24 MB)
#define OFF_CN  10485760          // cnorm fp32 [10240]
#define OFF_KEY 10526720          // candKey u64 [16384][8]
#define OFF_C2  11575296          // cand2 u32 [16384][8]
#define OFF_IDX 12099584
#define OFF_RL  12165120
#define OFF_CNT 12230656

__device__ __forceinline__ unsigned short f2bf(float f) {   // RNE fp32->bf16
    unsigned u = __float_as_uint(f);
    return (unsigned short)((u + 0x7fffu + ((u >> 16) & 1u)) >> 16);
}
__device__ __forceinline__ float bf2f(unsigned short h) {
    return __uint_as_float(((unsigned)h) << 16);
}
__device__ __forceinline__ unsigned ordf(float f) {         // order-preserving fp32->u32
    unsigned u = __float_as_uint(f);
    return (u & 0x80000000u) ? ~u : (u | 0x80000000u);
}
__device__ __forceinline__ float unordf(unsigned o) {
    return __uint_as_float((o & 0x80000000u) ? (o ^ 0x80000000u) : ~o);
}

// ---- prep: cnorm (exact fp32) + zero loss/counter ----
__global__ __launch_bounds__(256) void prep_norm(const float* __restrict__ C,
                                                 float* __restrict__ cnorm,
                                                 float* __restrict__ out,
                                                 int* __restrict__ counter) {
    int j = blockIdx.x * 256 + threadIdx.x;
    if (j == 0) { out[OUT_ELEMS] = 0.f; *counter = 0; }
    if (j >= NCODE_PAD) return;
    if (j >= NCODE) { cnorm[j] = 3.0e38f; return; }
    float s = 0.f;
#pragma unroll 8
    for (int d = 0; d < EMBED; ++d) {
        float v = C[d * NCODE + j];
        s = fmaf(v, v, s);
    }
    cnorm[j] = s;
}

// ---- prep: codes -> split-bf16 A-streams (swizzled) + CT fp32 [n][k] ----
// layout per chunk: [mb][ks][kh][row32][8]
__global__ __launch_bounds__(256) void prep_c4(const float* __restrict__ C,
                                               ushort_t* __restrict__ Ah,
                                               ushort_t* __restrict__ Al,
                                               float* __restrict__ CT) {
    int o = blockIdx.x * 256 + threadIdx.x;   // 163840 threads
    int n  = o % NCODE_PAD;
    int kg = o / NCODE_PAD;                   // 0..15
    int split = n / SPLIT_CODES;
    int rem   = n % SPLIT_CODES;
    int chunk = rem >> 6;
    int mb    = (rem >> 5) & 1;
    int row   = rem & 31;
    int ks = kg >> 1, kh = kg & 1;
    size_t eoff = (size_t)(split * NCHUNK + chunk) * CHUNK_ELEMS
                + (size_t)(mb * 4096 + (ks * 2 + kh) * 256 + row * 8);
    int k0 = kg * 8;
    float f[8];
#pragma unroll
    for (int j = 0; j < 8; ++j)
        f[j] = (n < NCODE) ? C[(size_t)(k0 + j) * NCODE + n] : 0.f;
    *(float4*)(CT + (size_t)n * EMBED + k0)     = make_float4(f[0], f[1], f[2], f[3]);
    *(float4*)(CT + (size_t)n * EMBED + k0 + 4) = make_float4(f[4], f[5], f[6], f[7]);
    s16x8 vh, vl;
#pragma unroll
    for (int j = 0; j < 8; ++j) {
        unsigned short h = f2bf(f[j]);
        vh[j] = (short)h;
        vl[j] = (short)f2bf(f[j] - bf2f(h));
    }
    *(s16x8*)(Ah + eoff) = vh;
    *(s16x8*)(Al + eoff) = vl;
}

// ---- main: persistent-X (B, -2x split h+l), codes (A, split h+l) LDS dbuf ----
// dist = cnorm (exact, epilogue) + [AhBh + AhBl + AlBh]. Argmin per-lane.
__global__ __launch_bounds__(256, 2) void vq6(const float* __restrict__ X,
                                              const ushort_t* __restrict__ Ah,
                                              const ushort_t* __restrict__ Al,
                                              const float* __restrict__ cnorm,
                                              u64* __restrict__ candKey,
                                              unsigned* __restrict__ cand2) {
    __shared__ ushort_t Bs[2 * 2 * CHUNK_ELEMS];   // 64 KB: buf{0,1} x {h,l}
    const int t    = threadIdx.x;
    const int lane = t & 63;
    const int wave = t >> 6;
    const int ln   = lane & 31;
    const int kh   = lane >> 5;
    const int split = blockIdx.y;
    const int m0    = blockIdx.x * 256;

    // ---- persistent B frags: (-2x) RNE-split hi+lo (128 VGPR) ----
    s16x8 bh[2][8], bl[2][8];
#pragma unroll
    for (int g = 0; g < 2; ++g) {
        int m = m0 + wave * 64 + g * 32 + ln;
#pragma unroll
        for (int ks = 0; ks < 8; ++ks) {
            const float* src = X + (size_t)m * EMBED + ks * 16 + kh * 8;
            float4 f0 = *(const float4*)src;
            float4 f1 = *(const float4*)(src + 4);
            float f[8] = {f0.x, f0.y, f0.z, f0.w, f1.x, f1.y, f1.z, f1.w};
            s16x8 vh, vl;
#pragma unroll
            for (int j = 0; j < 8; ++j) {
                float v = -2.f * f[j];
                unsigned short h = f2bf(v);
                vh[j] = (short)h;
                vl[j] = (short)f2bf(v - bf2f(h));
            }
            bh[g][ks] = vh;
            bl[g][ks] = vl;
        }
    }

    float v1[2] = {3.4e38f, 3.4e38f}, v2[2] = {3.4e38f, 3.4e38f};
    int   j1[2] = {0, 0};

    auto ldsw = (__attribute__((address_space(3))) ushort_t*)Bs;
    const int woff = wave * 2048;              // 4 KB slice per wave per {h,l}
    const size_t chbase = (size_t)(split * NCHUNK) * CHUNK_ELEMS;

    // ---- stage chunk 0 into buf 0 (h and l) ----
    {
        const ushort_t* sh = Ah + chbase + woff + lane * 8;
        const ushort_t* sl = Al + chbase + woff + lane * 8;
#pragma unroll
        for (int i = 0; i < 4; ++i) {
            __builtin_amdgcn_global_load_lds(
                (const __attribute__((address_space(1))) void*)(sh + i * 512),
                (__attribute__((address_space(3))) void*)(ldsw + woff + i * 512),
                16, 0, 0);
            __builtin_amdgcn_global_load_lds(
                (const __attribute__((address_space(1))) void*)(sl + i * 512),
                (__attribute__((address_space(3))) void*)(ldsw + CHUNK_ELEMS + woff + i * 512),
                16, 0, 0);
        }
    }
    __syncthreads();

    for (int c = 0; c < NCHUNK; ++c) {
        const int b = c & 1;
        // ---- prefetch chunk c+1 into the other buffer (async) ----
        if (c + 1 < NCHUNK) {
            const size_t sb = chbase + (size_t)(c + 1) * CHUNK_ELEMS;
            const ushort_t* sh = Ah + sb + woff + lane * 8;
            const ushort_t* sl = Al + sb + woff + lane * 8;
            const int db = (1 - b) * 2 * CHUNK_ELEMS + woff;
#pragma unroll
            for (int i = 0; i < 4; ++i) {
                __builtin_amdgcn_global_load_lds(
                    (const __attribute__((address_space(1))) void*)(sh + i * 512),
                    (__attribute__((address_space(3))) void*)(ldsw + db + i * 512),
                    16, 0, 0);
                __builtin_amdgcn_global_load_lds(
                    (const __attribute__((address_space(1))) void*)(sl + i * 512),
                    (__attribute__((address_space(3))) void*)(ldsw + db + CHUNK_ELEMS + i * 512),
                    16, 0, 0);
            }
        }

        // ---- compute chunk c: 96 MFMA, 32 ds_read_b128, <=2 A-frags live ----
        const int bb = b * 2 * CHUNK_ELEMS;
        f32x16 acc00 = {0,0,0,0,0,0,0,0,0,0,0,0,0,0,0,0};
        f32x16 acc01 = {0,0,0,0,0,0,0,0,0,0,0,0,0,0,0,0};
        f32x16 acc10 = {0,0,0,0,0,0,0,0,0,0,0,0,0,0,0,0};
        f32x16 acc11 = {0,0,0,0,0,0,0,0,0,0,0,0,0,0,0,0};
#pragma unroll
        for (int ks = 0; ks < 8; ++ks) {
            const int fo = bb + (ks * 2 + kh) * 256 + ln * 8;
            {   // mb = 0
                s16x8 a_h = *(const s16x8*)&Bs[fo];
                s16x8 a_l = *(const s16x8*)&Bs[CHUNK_ELEMS + fo];
                acc00 = __builtin_amdgcn_mfma_f32_32x32x16_bf16(a_h, bh[0][ks], acc00, 0, 0, 0);
                acc01 = __builtin_amdgcn_mfma_f32_32x32x16_bf16(a_h, bh[1][ks], acc01, 0, 0, 0);
                acc00 = __builtin_amdgcn_mfma_f32_32x32x16_bf16(a_h, bl[0][ks], acc00, 0, 0, 0);
                acc01 = __builtin_amdgcn_mfma_f32_32x32x16_bf16(a_h, bl[1][ks], acc01, 0, 0, 0);
                acc00 = __builtin_amdgcn_mfma_f32_32x32x16_bf16(a_l, bh[0][ks], acc00, 0, 0, 0);
                acc01 = __builtin_amdgcn_mfma_f32_32x32x16_bf16(a_l, bh[1][ks], acc01, 0, 0, 0);
            }
            {   // mb = 1
                s16x8 a_h = *(const s16x8*)&Bs[fo + 4096];
                s16x8 a_l = *(const s16x8*)&Bs[CHUNK_ELEMS + fo + 4096];
                acc10 = __builtin_amdgcn_mfma_f32_32x32x16_bf16(a_h, bh[0][ks], acc10, 0, 0, 0);
                acc11 = __builtin_amdgcn_mfma_f32_32x32x16_bf16(a_h, bh[1][ks], acc11, 0, 0, 0);
                acc10 = __builtin_amdgcn_mfma_f32_32x32x16_bf16(a_h, bl[0][ks], acc10, 0, 0, 0);
                acc11 = __builtin_amdgcn_mfma_f32_32x32x16_bf16(a_h, bl[1][ks], acc11, 0, 0, 0);
                acc10 = __builtin_amdgcn_mfma_f32_32x32x16_bf16(a_l, bh[0][ks], acc10, 0, 0, 0);
                acc11 = __builtin_amdgcn_mfma_f32_32x32x16_bf16(a_l, bh[1][ks], acc11, 0, 0, 0);
            }
        }

        // ---- epilogue: d = acc + exact cnorm; per-lane top-2 (no shuffles) ----
        const int cbase = split * SPLIT_CODES + c * 64 + 4 * kh;
#pragma unroll
        for (int r = 0; r < 16; ++r) {
            const int off = (r & 3) + 8 * (r >> 2);
            const int code0 = cbase + off;        // mb=0
            const int code1 = code0 + 32;         // mb=1
            const float cn0 = cnorm[code0];       // 256-B window, L1-hot
            const float cn1 = cnorm[code1];
            float d;
            d = acc00[r] + cn0;
            if (d < v1[0]) { v2[0] = v1[0]; v1[0] = d; j1[0] = code0; }
            else           { v2[0] = fminf(v2[0], d); }
            d = acc10[r] + cn1;
            if (d < v1[0]) { v2[0] = v1[0]; v1[0] = d; j1[0] = code1; }
            else           { v2[0] = fminf(v2[0], d); }
            d = acc01[r] + cn0;
            if (d < v1[1]) { v2[1] = v1[1]; v1[1] = d; j1[1] = code0; }
            else           { v2[1] = fminf(v2[1], d); }
            d = acc11[r] + cn1;
            if (d < v1[1]) { v2[1] = v1[1]; v1[1] = d; j1[1] = code1; }
            else           { v2[1] = fminf(v2[1], d); }
        }
        __syncthreads();   // buf b reads done; prefetch into 1-b drained
    }

    // merge lane^32 (same sample, other code-subset), emit per-split top-2
#pragma unroll
    for (int g = 0; g < 2; ++g) {
        float ov1 = __shfl_xor(v1[g], 32, 64);
        int   oj1 = __shfl_xor(j1[g], 32, 64);
        float ov2 = __shfl_xor(v2[g], 32, 64);
        float hi = fmaxf(v1[g], ov1);
        v2[g] = fminf(fminf(v2[g], ov2), hi);
        if (ov1 < v1[g] || (ov1 == v1[g] && oj1 < j1[g])) { v1[g] = ov1; j1[g] = oj1; }
        if (kh == 0) {
            int m = m0 + wave * 64 + g * 32 + ln;
            candKey[(size_t)m * NSPLIT + split] =
                ((u64)ordf(v1[g]) << 32) | (unsigned)j1[g];
            cand2[(size_t)m * NSPLIT + split] = ordf(v2[g]);
        }
    }
}

// ---- fused finalize + output: merge 8 candidates, flag near-ties, gather, loss ----
__global__ __launch_bounds__(256) void outfin_k(const float* __restrict__ X,
                                                const float* __restrict__ CT,
                                                const u64* __restrict__ candKey,
                                                const unsigned* __restrict__ cand2,
                                                int* __restrict__ idxf,
                                                int* __restrict__ rlist,
                                                int* __restrict__ counter,
                                                float* __restrict__ out) {
    __shared__ float red[4];
    const int t = threadIdx.x;
    const int m = blockIdx.x * 8 + (t >> 5);
    const int l = t & 31;

    int code = 0;
    if (l == 0) {
        u64 best = 0xffffffffffffffffull;
        float v2 = 3.4e38f;
#pragma unroll
        for (int s = 0; s < NSPLIT; ++s) {
            u64 k = candKey[(size_t)m * NSPLIT + s];
            unsigned o2 = cand2[(size_t)m * NSPLIT + s];
            if (k < best) {
                if (best != 0xffffffffffffffffull)
                    v2 = fminf(v2, unordf((unsigned)(best >> 32)));
                best = k;
                v2 = fminf(v2, unordf(o2));
            } else {
                v2 = fminf(v2, unordf((unsigned)(k >> 32)));
            }
        }
        code = (int)(unsigned)(best & 0xffffffffu);
        idxf[m] = code;
        float v1 = unordf((unsigned)(best >> 32));
        if (v2 - v1 <= TAU) rlist[atomicAdd(counter, 1)] = m;
    }
    code = __shfl(code, 0, 32);

    float4 q = *(const float4*)(CT + (size_t)code * EMBED + l * 4);
    float4 x = *(const float4*)(X + (size_t)m * EMBED + l * 4);
    *(float4*)(out + (size_t)m * EMBED + l * 4) = q;
    float dx = q.x - x.x, dy = q.y - x.y, dz = q.z - x.z, dw = q.w - x.w;
    float lsum = dx * dx + dy * dy + dz * dz + dw * dw;
#pragma unroll
    for (int off = 1; off < 64; off <<= 1) lsum += __shfl_xor(lsum, off, 64);
    if ((t & 63) == 0) red[t >> 6] = lsum;
    __syncthreads();
    if (t == 0)
        atomicAdd(out + OUT_ELEMS,
                  (red[0] + red[1] + red[2] + red[3]) * (1.25f / (float)OUT_ELEMS));
}

// ---- rescue: exact fp32 argmin, one block per flagged sample, 2-row ILP ----
__global__ __launch_bounds__(256) void rescue_one(const float* __restrict__ X,
                                                  const float* __restrict__ CT,
                                                  const float* __restrict__ cnorm,
                                                  const int* __restrict__ rlist,
                                                  const int* __restrict__ counter,
                                                  const int* __restrict__ idxf,
                                                  float* __restrict__ out) {
    __shared__ float xs[EMBED];
    __shared__ u64 wk[4];
    __shared__ int sjn;
    const int t = threadIdx.x;
    const int lane = t & 63;
    const int wave = t >> 6;
    const int hw = t & 31;       // lane within half-wave
    const int rowoff = t >> 5;   // 0..7
    const int cnt = *counter;

    for (int s = blockIdx.x; s < cnt; s += gridDim.x) {
        const int m = rlist[s];
        __syncthreads();   // previous iteration's xs/wk reads complete
        if (t < 32) {
            float4 v = *(const float4*)(X + (size_t)m * EMBED + t * 4);
            xs[t * 4 + 0] = v.x; xs[t * 4 + 1] = v.y;
            xs[t * 4 + 2] = v.z; xs[t * 4 + 3] = v.w;
        }
        __syncthreads();
        const float x0 = xs[hw * 4 + 0], x1 = xs[hw * 4 + 1];
        const float x2 = xs[hw * 4 + 2], x3 = xs[hw * 4 + 3];
        u64 bk = 0xffffffffffffffffull;
        for (int it = 0; it < 625; ++it) {
            int r0 = it * 16 + rowoff * 2;       // covers 0..9999 exactly
            int r1 = r0 + 1;
            float4 c0 = *(const float4*)(CT + (size_t)r0 * EMBED + hw * 4);
            float4 c1 = *(const float4*)(CT + (size_t)r1 * EMBED + hw * 4);
            float p0 = x0 * c0.x;
            float p1 = x0 * c1.x;
            p0 = fmaf(x1, c0.y, p0);  p1 = fmaf(x1, c1.y, p1);
            p0 = fmaf(x2, c0.z, p0);  p1 = fmaf(x2, c1.z, p1);
            p0 = fmaf(x3, c0.w, p0);  p1 = fmaf(x3, c1.w, p1);
#pragma unroll
            for (int off = 1; off < 32; off <<= 1) {
                p0 += __shfl_xor(p0, off, 32);
                p1 += __shfl_xor(p1, off, 32);
            }
            if (hw == 0) {
                float d0 = fmaf(-2.f, p0, cnorm[r0]);
                float d1 = fmaf(-2.f, p1, cnorm[r1]);
                u64 k0 = ((u64)ordf(d0) << 32) | (unsigned)r0;
                u64 k1 = ((u64)ordf(d1) << 32) | (unsigned)r1;
                if (k0 < bk) bk = k0;
                if (k1 < bk) bk = k1;
            }
        }
#pragma unroll
        for (int off = 1; off < 64; off <<= 1) {
            u64 o = __shfl_xor(bk, off, 64);
            if (o < bk) bk = o;
        }
        if (lane == 0) wk[wave] = bk;
        __syncthreads();
        if (t == 0) {
            u64 b = wk[0];
            if (wk[1] < b) b = wk[1];
            if (wk[2] < b) b = wk[2];
            if (wk[3] < b) b = wk[3];
            sjn = (int)(unsigned)(b & 0xffffffffu);
        }
        __syncthreads();
        const int jn = sjn;
        const int jo = idxf[m];
        if (jn != jo) {
            if (t < 32) {
                float4 qn = *(const float4*)(CT + (size_t)jn * EMBED + t * 4);
                float4 qo = *(const float4*)(CT + (size_t)jo * EMBED + t * 4);
                float xa = xs[t * 4 + 0], xb = xs[t * 4 + 1];
                float xc = xs[t * 4 + 2], xd = xs[t * 4 + 3];
                *(float4*)(out + (size_t)m * EMBED + t * 4) = qn;
                float dn = (qn.x - xa) * (qn.x - xa) + (qn.y - xb) * (qn.y - xb)
                         + (qn.z - xc) * (qn.z - xc) + (qn.w - xd) * (qn.w - xd);
                float dp = (qo.x - xa) * (qo.x - xa) + (qo.y - xb) * (qo.y - xb)
                         + (qo.z - xc) * (qo.z - xc) + (qo.w - xd) * (qo.w - xd);
                float delta = dn - dp;
#pragma unroll
                for (int off = 1; off < 32; off <<= 1)
                    delta += __shfl_xor(delta, off, 32);
                if (t == 0)
                    atomicAdd(out + OUT_ELEMS, delta * (1.25f / (float)OUT_ELEMS));
            }
        }
    }
}

extern "C" void kernel_launch(void* const* d_in, const int* in_sizes, int n_in,
                              void* d_out, int out_size, void* d_ws, size_t ws_size,
                              hipStream_t stream) {
    const float* X = (const float*)d_in[0];   // (16384,128) fp32
    const float* C = (const float*)d_in[1];   // (128,10000) fp32
    float* out = (float*)d_out;
    char* ws = (char*)d_ws;

    ushort_t* Ah = (ushort_t*)(ws + OFF_AH);
    ushort_t* Al = (ushort_t*)(ws + OFF_AL);
    float* CT    = (float*)(ws + OFF_CT);
    float* cnorm = (float*)(ws + OFF_CN);
    u64* candKey = (u64*)(ws + OFF_KEY);
    unsigned* cand2 = (unsigned*)(ws + OFF_C2);
    int* idxf    = (int*)(ws + OFF_IDX);
    int* rlist   = (int*)(ws + OFF_RL);
    int* counter = (int*)(ws + OFF_CNT);

    prep_norm<<<NCODE_PAD / 256, 256, 0, stream>>>(C, cnorm, out, counter);
    prep_c4<<<(NCODE_PAD * 16) / 256, 256, 0, stream>>>(C, Ah, Al, CT);
    vq6<<<dim3(NSAMP / 256, NSPLIT), 256, 0, stream>>>(X, Ah, Al, cnorm, candKey, cand2);
    outfin_k<<<NSAMP / 8, 256, 0, stream>>>(X, CT, candKey, cand2, idxf, rlist, counter, out);
    rescue_one<<<512, 256, 0, stream>>>(X, CT, cnorm, rlist, counter, idxf, out);
}

// Round 10
// 261.027 us; speedup vs baseline: 5.6797x; 2.4873x over previous
//
#include <hip/hip_runtime.h>

#define EMBED 128
#define NCODE 10000
#define NSAMP 16384
#define NCODE_PAD 10240
#define NSPLIT 8
#define SPLIT_CODES 1280
#define NCHUNK 20                 // chunks per split, 64 codes each
#define CHUNK_ELEMS 8192          // ushorts per chunk per (h|l): 2mb*8ks*2kh*256
#define OUT_ELEMS (NSAMP * EMBED)
#define TAU 0.002f                // ~28 sigma of full split-bf16 pairwise error
#define NSEG 16                   // rescue segments (625 codes each)

typedef float f32x16 __attribute__((ext_vector_type(16)));
typedef short s16x8 __attribute__((ext_vector_type(8)));
typedef unsigned short ushort_t;
typedef unsigned long long u64;

// ---- ws byte offsets (~12.5 MB) ----
#define OFF_AH  0                 // codes hi bf16, swizzled (2.62 MB)
#define OFF_AL  2621440           // codes lo bf16
#define OFF_CT  5242880           // CT fp32 [n][k] (5.24 MB)
#define OFF_CN  10485760          // cnorm fp32 [10240]
#define OFF_KEY 10526720          // candKey u64 [16384][8]
#define OFF_C2  11575296          // cand2 u32 [16384][8]
#define OFF_IDX 12099584
#define OFF_RL  12165120
#define OFF_CNT 12230656
#define OFF_BEST 12230720         // wsBest u64 [16384]

__device__ __forceinline__ unsigned short f2bf(float f) {   // RNE fp32->bf16
    unsigned u = __float_as_uint(f);
    return (unsigned short)((u + 0x7fffu + ((u >> 16) & 1u)) >> 16);
}
__device__ __forceinline__ float bf2f(unsigned short h) {
    return __uint_as_float(((unsigned)h) << 16);
}
__device__ __forceinline__ unsigned ordf(float f) {         // order-preserving fp32->u32
    unsigned u = __float_as_uint(f);
    return (u & 0x80000000u) ? ~u : (u | 0x80000000u);
}
__device__ __forceinline__ float unordf(unsigned o) {
    return __uint_as_float((o & 0x80000000u) ? (o ^ 0x80000000u) : ~o);
}

// ---- prep: cnorm (exact fp32) + zero loss/counter ----
__global__ __launch_bounds__(256) void prep_norm(const float* __restrict__ C,
                                                 float* __restrict__ cnorm,
                                                 float* __restrict__ out,
                                                 int* __restrict__ counter) {
    int j = blockIdx.x * 256 + threadIdx.x;
    if (j == 0) { out[OUT_ELEMS] = 0.f; *counter = 0; }
    if (j >= NCODE_PAD) return;
    if (j >= NCODE) { cnorm[j] = 3.0e38f; return; }
    float s = 0.f;
#pragma unroll 8
    for (int d = 0; d < EMBED; ++d) {
        float v = C[d * NCODE + j];
        s = fmaf(v, v, s);
    }
    cnorm[j] = s;
}

// ---- prep: codes -> split-bf16 A-streams (swizzled) + CT fp32 [n][k] ----
// layout per chunk: [mb][ks][kh][row32][8]
__global__ __launch_bounds__(256) void prep_c4(const float* __restrict__ C,
                                               ushort_t* __restrict__ Ah,
                                               ushort_t* __restrict__ Al,
                                               float* __restrict__ CT) {
    int o = blockIdx.x * 256 + threadIdx.x;   // 163840 threads
    int n  = o % NCODE_PAD;
    int kg = o / NCODE_PAD;                   // 0..15
    int split = n / SPLIT_CODES;
    int rem   = n % SPLIT_CODES;
    int chunk = rem >> 6;
    int mb    = (rem >> 5) & 1;
    int row   = rem & 31;
    int ks = kg >> 1, kh = kg & 1;
    size_t eoff = (size_t)(split * NCHUNK + chunk) * CHUNK_ELEMS
                + (size_t)(mb * 4096 + (ks * 2 + kh) * 256 + row * 8);
    int k0 = kg * 8;
    float f[8];
#pragma unroll
    for (int j = 0; j < 8; ++j)
        f[j] = (n < NCODE) ? C[(size_t)(k0 + j) * NCODE + n] : 0.f;
    *(float4*)(CT + (size_t)n * EMBED + k0)     = make_float4(f[0], f[1], f[2], f[3]);
    *(float4*)(CT + (size_t)n * EMBED + k0 + 4) = make_float4(f[4], f[5], f[6], f[7]);
    s16x8 vh, vl;
#pragma unroll
    for (int j = 0; j < 8; ++j) {
        unsigned short h = f2bf(f[j]);
        vh[j] = (short)h;
        vl[j] = (short)f2bf(f[j] - bf2f(h));
    }
    *(s16x8*)(Ah + eoff) = vh;
    *(s16x8*)(Al + eoff) = vl;
}

// ---- main: persistent-X (B, -2x split h+l), codes (A, split h+l) LDS dbuf ----
// dist = cnorm (exact, epilogue) + [AhBh + AhBl + AlBh]. Argmin per-lane.
__global__ __launch_bounds__(256, 2) void vq6(const float* __restrict__ X,
                                              const ushort_t* __restrict__ Ah,
                                              const ushort_t* __restrict__ Al,
                                              const float* __restrict__ cnorm,
                                              u64* __restrict__ candKey,
                                              unsigned* __restrict__ cand2) {
    __shared__ ushort_t Bs[2 * 2 * CHUNK_ELEMS];   // 64 KB: buf{0,1} x {h,l}
    const int t    = threadIdx.x;
    const int lane = t & 63;
    const int wave = t >> 6;
    const int ln   = lane & 31;
    const int kh   = lane >> 5;
    const int split = blockIdx.y;
    const int m0    = blockIdx.x * 256;

    // ---- persistent B frags: (-2x) RNE-split hi+lo (128 VGPR) ----
    s16x8 bh[2][8], bl[2][8];
#pragma unroll
    for (int g = 0; g < 2; ++g) {
        int m = m0 + wave * 64 + g * 32 + ln;
#pragma unroll
        for (int ks = 0; ks < 8; ++ks) {
            const float* src = X + (size_t)m * EMBED + ks * 16 + kh * 8;
            float4 f0 = *(const float4*)src;
            float4 f1 = *(const float4*)(src + 4);
            float f[8] = {f0.x, f0.y, f0.z, f0.w, f1.x, f1.y, f1.z, f1.w};
            s16x8 vh, vl;
#pragma unroll
            for (int j = 0; j < 8; ++j) {
                float v = -2.f * f[j];
                unsigned short h = f2bf(v);
                vh[j] = (short)h;
                vl[j] = (short)f2bf(v - bf2f(h));
            }
            bh[g][ks] = vh;
            bl[g][ks] = vl;
        }
    }

    float v1[2] = {3.4e38f, 3.4e38f}, v2[2] = {3.4e38f, 3.4e38f};
    int   j1[2] = {0, 0};

    auto ldsw = (__attribute__((address_space(3))) ushort_t*)Bs;
    const int woff = wave * 2048;              // 4 KB slice per wave per {h,l}
    const size_t chbase = (size_t)(split * NCHUNK) * CHUNK_ELEMS;

    // ---- stage chunk 0 into buf 0 (h and l) ----
    {
        const ushort_t* sh = Ah + chbase + woff + lane * 8;
        const ushort_t* sl = Al + chbase + woff + lane * 8;
#pragma unroll
        for (int i = 0; i < 4; ++i) {
            __builtin_amdgcn_global_load_lds(
                (const __attribute__((address_space(1))) void*)(sh + i * 512),
                (__attribute__((address_space(3))) void*)(ldsw + woff + i * 512),
                16, 0, 0);
            __builtin_amdgcn_global_load_lds(
                (const __attribute__((address_space(1))) void*)(sl + i * 512),
                (__attribute__((address_space(3))) void*)(ldsw + CHUNK_ELEMS + woff + i * 512),
                16, 0, 0);
        }
    }
    __syncthreads();

    for (int c = 0; c < NCHUNK; ++c) {
        const int b = c & 1;
        // ---- prefetch chunk c+1 into the other buffer (async) ----
        if (c + 1 < NCHUNK) {
            const size_t sb = chbase + (size_t)(c + 1) * CHUNK_ELEMS;
            const ushort_t* sh = Ah + sb + woff + lane * 8;
            const ushort_t* sl = Al + sb + woff + lane * 8;
            const int db = (1 - b) * 2 * CHUNK_ELEMS + woff;
#pragma unroll
            for (int i = 0; i < 4; ++i) {
                __builtin_amdgcn_global_load_lds(
                    (const __attribute__((address_space(1))) void*)(sh + i * 512),
                    (__attribute__((address_space(3))) void*)(ldsw + db + i * 512),
                    16, 0, 0);
                __builtin_amdgcn_global_load_lds(
                    (const __attribute__((address_space(1))) void*)(sl + i * 512),
                    (__attribute__((address_space(3))) void*)(ldsw + db + CHUNK_ELEMS + i * 512),
                    16, 0, 0);
            }
        }

        // ---- compute chunk c: 96 MFMA, 32 ds_read_b128, <=2 A-frags live ----
        const int bb = b * 2 * CHUNK_ELEMS;
        f32x16 acc00 = {0,0,0,0,0,0,0,0,0,0,0,0,0,0,0,0};
        f32x16 acc01 = {0,0,0,0,0,0,0,0,0,0,0,0,0,0,0,0};
        f32x16 acc10 = {0,0,0,0,0,0,0,0,0,0,0,0,0,0,0,0};
        f32x16 acc11 = {0,0,0,0,0,0,0,0,0,0,0,0,0,0,0,0};
#pragma unroll
        for (int ks = 0; ks < 8; ++ks) {
            const int fo = bb + (ks * 2 + kh) * 256 + ln * 8;
            {   // mb = 0
                s16x8 a_h = *(const s16x8*)&Bs[fo];
                s16x8 a_l = *(const s16x8*)&Bs[CHUNK_ELEMS + fo];
                acc00 = __builtin_amdgcn_mfma_f32_32x32x16_bf16(a_h, bh[0][ks], acc00, 0, 0, 0);
                acc01 = __builtin_amdgcn_mfma_f32_32x32x16_bf16(a_h, bh[1][ks], acc01, 0, 0, 0);
                acc00 = __builtin_amdgcn_mfma_f32_32x32x16_bf16(a_h, bl[0][ks], acc00, 0, 0, 0);
                acc01 = __builtin_amdgcn_mfma_f32_32x32x16_bf16(a_h, bl[1][ks], acc01, 0, 0, 0);
                acc00 = __builtin_amdgcn_mfma_f32_32x32x16_bf16(a_l, bh[0][ks], acc00, 0, 0, 0);
                acc01 = __builtin_amdgcn_mfma_f32_32x32x16_bf16(a_l, bh[1][ks], acc01, 0, 0, 0);
            }
            {   // mb = 1
                s16x8 a_h = *(const s16x8*)&Bs[fo + 4096];
                s16x8 a_l = *(const s16x8*)&Bs[CHUNK_ELEMS + fo + 4096];
                acc10 = __builtin_amdgcn_mfma_f32_32x32x16_bf16(a_h, bh[0][ks], acc10, 0, 0, 0);
                acc11 = __builtin_amdgcn_mfma_f32_32x32x16_bf16(a_h, bh[1][ks], acc11, 0, 0, 0);
                acc10 = __builtin_amdgcn_mfma_f32_32x32x16_bf16(a_h, bl[0][ks], acc10, 0, 0, 0);
                acc11 = __builtin_amdgcn_mfma_f32_32x32x16_bf16(a_h, bl[1][ks], acc11, 0, 0, 0);
                acc10 = __builtin_amdgcn_mfma_f32_32x32x16_bf16(a_l, bh[0][ks], acc10, 0, 0, 0);
                acc11 = __builtin_amdgcn_mfma_f32_32x32x16_bf16(a_l, bh[1][ks], acc11, 0, 0, 0);
            }
        }

        // ---- epilogue: d = acc + exact cnorm; per-lane top-2 (no shuffles) ----
        const int cbase = split * SPLIT_CODES + c * 64 + 4 * kh;
#pragma unroll
        for (int r = 0; r < 16; ++r) {
            const int off = (r & 3) + 8 * (r >> 2);
            const int code0 = cbase + off;        // mb=0
            const int code1 = code0 + 32;         // mb=1
            const float cn0 = cnorm[code0];       // 256-B window, L1-hot
            const float cn1 = cnorm[code1];
            float d;
            d = acc00[r] + cn0;
            if (d < v1[0]) { v2[0] = v1[0]; v1[0] = d; j1[0] = code0; }
            else           { v2[0] = fminf(v2[0], d); }
            d = acc10[r] + cn1;
            if (d < v1[0]) { v2[0] = v1[0]; v1[0] = d; j1[0] = code1; }
            else           { v2[0] = fminf(v2[0], d); }
            d = acc01[r] + cn0;
            if (d < v1[1]) { v2[1] = v1[1]; v1[1] = d; j1[1] = code0; }
            else           { v2[1] = fminf(v2[1], d); }
            d = acc11[r] + cn1;
            if (d < v1[1]) { v2[1] = v1[1]; v1[1] = d; j1[1] = code1; }
            else           { v2[1] = fminf(v2[1], d); }
        }
        __syncthreads();   // buf b reads done; prefetch into 1-b drained
    }

    // merge lane^32 (same sample, other code-subset), emit per-split top-2
#pragma unroll
    for (int g = 0; g < 2; ++g) {
        float ov1 = __shfl_xor(v1[g], 32, 64);
        int   oj1 = __shfl_xor(j1[g], 32, 64);
        float ov2 = __shfl_xor(v2[g], 32, 64);
        float hi = fmaxf(v1[g], ov1);
        v2[g] = fminf(fminf(v2[g], ov2), hi);
        if (ov1 < v1[g] || (ov1 == v1[g] && oj1 < j1[g])) { v1[g] = ov1; j1[g] = oj1; }
        if (kh == 0) {
            int m = m0 + wave * 64 + g * 32 + ln;
            candKey[(size_t)m * NSPLIT + split] =
                ((u64)ordf(v1[g]) << 32) | (unsigned)j1[g];
            cand2[(size_t)m * NSPLIT + split] = ordf(v2[g]);
        }
    }
}

// ---- fused finalize + output: merge 8 candidates, flag near-ties, gather, loss ----
__global__ __launch_bounds__(256) void outfin_k(const float* __restrict__ X,
                                                const float* __restrict__ CT,
                                                const u64* __restrict__ candKey,
                                                const unsigned* __restrict__ cand2,
                                                int* __restrict__ idxf,
                                                int* __restrict__ rlist,
                                                int* __restrict__ counter,
                                                u64* __restrict__ wsBest,
                                                float* __restrict__ out) {
    __shared__ float red[4];
    const int t = threadIdx.x;
    const int m = blockIdx.x * 8 + (t >> 5);
    const int l = t & 31;

    int code = 0;
    if (l == 0) {
        u64 best = 0xffffffffffffffffull;
        float v2 = 3.4e38f;
#pragma unroll
        for (int s = 0; s < NSPLIT; ++s) {
            u64 k = candKey[(size_t)m * NSPLIT + s];
            unsigned o2 = cand2[(size_t)m * NSPLIT + s];
            if (k < best) {
                if (best != 0xffffffffffffffffull)
                    v2 = fminf(v2, unordf((unsigned)(best >> 32)));
                best = k;
                v2 = fminf(v2, unordf(o2));
            } else {
                v2 = fminf(v2, unordf((unsigned)(k >> 32)));
            }
        }
        code = (int)(unsigned)(best & 0xffffffffu);
        idxf[m] = code;
        float v1 = unordf((unsigned)(best >> 32));
        if (v2 - v1 <= TAU) {
            rlist[atomicAdd(counter, 1)] = m;
            wsBest[m] = 0xffffffffffffffffull;   // init for rescue atomicMin
        }
    }
    code = __shfl(code, 0, 32);

    float4 q = *(const float4*)(CT + (size_t)code * EMBED + l * 4);
    float4 x = *(const float4*)(X + (size_t)m * EMBED + l * 4);
    *(float4*)(out + (size_t)m * EMBED + l * 4) = q;
    float dx = q.x - x.x, dy = q.y - x.y, dz = q.z - x.z, dw = q.w - x.w;
    float lsum = dx * dx + dy * dy + dz * dz + dw * dw;
#pragma unroll
    for (int off = 1; off < 64; off <<= 1) lsum += __shfl_xor(lsum, off, 64);
    if ((t & 63) == 0) red[t >> 6] = lsum;
    __syncthreads();
    if (t == 0)
        atomicAdd(out + OUT_ELEMS,
                  (red[0] + red[1] + red[2] + red[3]) * (1.25f / (float)OUT_ELEMS));
}

// ---- rescue: exact fp32 argmin; work unit = (flagged sample, 625-code seg) ----
// 8 row-slots x 4-row ILP = 32 rows in flight per block iteration (20 iters).
__global__ __launch_bounds__(256) void rescue_seg(const float* __restrict__ X,
                                                  const float* __restrict__ CT,
                                                  const float* __restrict__ cnorm,
                                                  const int* __restrict__ rlist,
                                                  const int* __restrict__ counter,
                                                  u64* __restrict__ wsBest) {
    __shared__ float xs[EMBED];
    __shared__ u64 wk[4];
    const int t = threadIdx.x;
    const int lane = t & 63;
    const int wave = t >> 6;
    const int hw = t & 31;       // lane within half-wave (dims hw*4..hw*4+3)
    const int slot = t >> 5;     // 0..7 row-slot
    const int cnt = *counter;
    const int nw = cnt * NSEG;

    for (int w = blockIdx.x; w < nw; w += gridDim.x) {
        const int s = w >> 4, seg = w & 15;
        const int m = rlist[s];
        __syncthreads();   // previous iteration's xs/wk reads complete
        if (t < 32) {
            float4 v = *(const float4*)(X + (size_t)m * EMBED + t * 4);
            xs[t * 4 + 0] = v.x; xs[t * 4 + 1] = v.y;
            xs[t * 4 + 2] = v.z; xs[t * 4 + 3] = v.w;
        }
        __syncthreads();
        const float x0 = xs[hw * 4 + 0], x1 = xs[hw * 4 + 1];
        const float x2 = xs[hw * 4 + 2], x3 = xs[hw * 4 + 3];
        const int base = seg * 625;          // 16*625 = 10000 exactly
        const int jend = base + 625;
        u64 bk = 0xffffffffffffffffull;
        for (int it = 0; it < 20; ++it) {
            const int r0 = base + it * 32 + slot * 4;
            float4 c0, c1, c2, c3;
            bool ok0 = (r0 + 0 < jend), ok1 = (r0 + 1 < jend);
            bool ok2 = (r0 + 2 < jend), ok3 = (r0 + 3 < jend);
            c0 = ok0 ? *(const float4*)(CT + (size_t)(r0 + 0) * EMBED + hw * 4) : make_float4(0, 0, 0, 0);
            c1 = ok1 ? *(const float4*)(CT + (size_t)(r0 + 1) * EMBED + hw * 4) : make_float4(0, 0, 0, 0);
            c2 = ok2 ? *(const float4*)(CT + (size_t)(r0 + 2) * EMBED + hw * 4) : make_float4(0, 0, 0, 0);
            c3 = ok3 ? *(const float4*)(CT + (size_t)(r0 + 3) * EMBED + hw * 4) : make_float4(0, 0, 0, 0);
            float p0 = x0 * c0.x, p1 = x0 * c1.x, p2 = x0 * c2.x, p3 = x0 * c3.x;
            p0 = fmaf(x1, c0.y, p0); p1 = fmaf(x1, c1.y, p1);
            p2 = fmaf(x1, c2.y, p2); p3 = fmaf(x1, c3.y, p3);
            p0 = fmaf(x2, c0.z, p0); p1 = fmaf(x2, c1.z, p1);
            p2 = fmaf(x2, c2.z, p2); p3 = fmaf(x2, c3.z, p3);
            p0 = fmaf(x3, c0.w, p0); p1 = fmaf(x3, c1.w, p1);
            p2 = fmaf(x3, c2.w, p2); p3 = fmaf(x3, c3.w, p3);
#pragma unroll
            for (int off = 1; off < 32; off <<= 1) {   // 4 interleaved chains
                p0 += __shfl_xor(p0, off, 32);
                p1 += __shfl_xor(p1, off, 32);
                p2 += __shfl_xor(p2, off, 32);
                p3 += __shfl_xor(p3, off, 32);
            }
            if (hw == 0) {
                if (ok0) { u64 k = ((u64)ordf(fmaf(-2.f, p0, cnorm[r0 + 0])) << 32) | (unsigned)(r0 + 0); if (k < bk) bk = k; }
                if (ok1) { u64 k = ((u64)ordf(fmaf(-2.f, p1, cnorm[r0 + 1])) << 32) | (unsigned)(r0 + 1); if (k < bk) bk = k; }
                if (ok2) { u64 k = ((u64)ordf(fmaf(-2.f, p2, cnorm[r0 + 2])) << 32) | (unsigned)(r0 + 2); if (k < bk) bk = k; }
                if (ok3) { u64 k = ((u64)ordf(fmaf(-2.f, p3, cnorm[r0 + 3])) << 32) | (unsigned)(r0 + 3); if (k < bk) bk = k; }
            }
        }
#pragma unroll
        for (int off = 1; off < 64; off <<= 1) {
            u64 o = __shfl_xor(bk, off, 64);
            if (o < bk) bk = o;
        }
        if (lane == 0) wk[wave] = bk;
        __syncthreads();
        if (t == 0) {
            u64 b = wk[0];
            if (wk[1] < b) b = wk[1];
            if (wk[2] < b) b = wk[2];
            if (wk[3] < b) b = wk[3];
            atomicMin(&wsBest[m], b);
        }
    }
}

// ---- patch: apply argmin flips found by rescue ----
__global__ __launch_bounds__(256) void patch_k(const float* __restrict__ X,
                                               const float* __restrict__ CT,
                                               const int* __restrict__ rlist,
                                               const int* __restrict__ counter,
                                               const u64* __restrict__ wsBest,
                                               const int* __restrict__ idxf,
                                               float* __restrict__ out) {
    const int t = threadIdx.x;
    const int l = t & 31, sl = t >> 5;
    const int cnt = *counter;
    for (int s = blockIdx.x * 8 + sl; s < cnt; s += gridDim.x * 8) {
        int m = rlist[s];
        u64 key = wsBest[m];
        int jn = (int)(unsigned)(key & 0xffffffffu);
        int jo = idxf[m];
        if (jn == jo) continue;   // uniform within 32-lane group
        float4 qn = *(const float4*)(CT + (size_t)jn * EMBED + l * 4);
        float4 qo = *(const float4*)(CT + (size_t)jo * EMBED + l * 4);
        float4 x  = *(const float4*)(X + (size_t)m * EMBED + l * 4);
        *(float4*)(out + (size_t)m * EMBED + l * 4) = qn;
        float dn = (qn.x - x.x) * (qn.x - x.x) + (qn.y - x.y) * (qn.y - x.y)
                 + (qn.z - x.z) * (qn.z - x.z) + (qn.w - x.w) * (qn.w - x.w);
        float dp = (qo.x - x.x) * (qo.x - x.x) + (qo.y - x.y) * (qo.y - x.y)
                 + (qo.z - x.z) * (qo.z - x.z) + (qo.w - x.w) * (qo.w - x.w);
        float delta = dn - dp;
#pragma unroll
        for (int off = 1; off < 32; off <<= 1) delta += __shfl_xor(delta, off, 32);
        if (l == 0)
            atomicAdd(out + OUT_ELEMS, delta * (1.25f / (float)OUT_ELEMS));
    }
}

extern "C" void kernel_launch(void* const* d_in, const int* in_sizes, int n_in,
                              void* d_out, int out_size, void* d_ws, size_t ws_size,
                              hipStream_t stream) {
    const float* X = (const float*)d_in[0];   // (16384,128) fp32
    const float* C = (const float*)d_in[1];   // (128,10000) fp32
    float* out = (float*)d_out;
    char* ws = (char*)d_ws;

    ushort_t* Ah = (ushort_t*)(ws + OFF_AH);
    ushort_t* Al = (ushort_t*)(ws + OFF_AL);
    float* CT    = (float*)(ws + OFF_CT);
    float* cnorm = (float*)(ws + OFF_CN);
    u64* candKey = (u64*)(ws + OFF_KEY);
    unsigned* cand2 = (unsigned*)(ws + OFF_C2);
    int* idxf    = (int*)(ws + OFF_IDX);
    int* rlist   = (int*)(ws + OFF_RL);
    int* counter = (int*)(ws + OFF_CNT);
    u64* wsBest  = (u64*)(ws + OFF_BEST);

    prep_norm<<<NCODE_PAD / 256, 256, 0, stream>>>(C, cnorm, out, counter);
    prep_c4<<<(NCODE_PAD * 16) / 256, 256, 0, stream>>>(C, Ah, Al, CT);
    vq6<<<dim3(NSAMP / 256, NSPLIT), 256, 0, stream>>>(X, Ah, Al, cnorm, candKey, cand2);
    outfin_k<<<NSAMP / 8, 256, 0, stream>>>(X, CT, candKey, cand2, idxf, rlist, counter, wsBest, out);
    rescue_seg<<<1024, 256, 0, stream>>>(X, CT, cnorm, rlist, counter, wsBest);
    patch_k<<<64, 256, 0, stream>>>(X, CT, rlist, counter, wsBest, idxf, out);
}

// Round 11
// 259.913 us; speedup vs baseline: 5.7040x; 1.0043x over previous
//
#include <hip/hip_runtime.h>

#define EMBED 128
#define NCODE 10000
#define NSAMP 16384
#define NCODE_PAD 10240
#define NSPLIT 8
#define SPLIT_CODES 1280
#define NCHUNK 20                 // chunks per split, 64 codes each
#define CHUNK_ELEMS 8192          // ushorts per chunk per (h|l): 2mb*8ks*2kh*256
#define OUT_ELEMS (NSAMP * EMBED)
#define TAU 0.002f                // ~28 sigma of full split-bf16 pairwise error
#define NSEG 16                   // rescue segments (625 codes each)

typedef float f32x16 __attribute__((ext_vector_type(16)));
typedef short s16x8 __attribute__((ext_vector_type(8)));
typedef unsigned short ushort_t;
typedef unsigned long long u64;

// ---- ws byte offsets (~12.5 MB) ----
#define OFF_AH  0                 // codes hi bf16, swizzled (2.62 MB)
#define OFF_AL  2621440           // codes lo bf16
#define OFF_CT  5242880           // CT fp32 [n][k] (5.24 MB)
#define OFF_CN  10485760          // cnorm fp32 [10240]
#define OFF_KEY 10526720          // candKey u64 [16384][8]
#define OFF_C2  11575296          // cand2 u32 [16384][8]
#define OFF_IDX 12099584
#define OFF_RL  12165120
#define OFF_CNT 12230656
#define OFF_BEST 12230720         // wsBest u64 [16384]

__device__ __forceinline__ unsigned short f2bf(float f) {   // RNE fp32->bf16
    unsigned u = __float_as_uint(f);
    return (unsigned short)((u + 0x7fffu + ((u >> 16) & 1u)) >> 16);
}
__device__ __forceinline__ float bf2f(unsigned short h) {
    return __uint_as_float(((unsigned)h) << 16);
}
__device__ __forceinline__ unsigned ordf(float f) {         // order-preserving fp32->u32
    unsigned u = __float_as_uint(f);
    return (u & 0x80000000u) ? ~u : (u | 0x80000000u);
}
__device__ __forceinline__ float unordf(unsigned o) {
    return __uint_as_float((o & 0x80000000u) ? (o ^ 0x80000000u) : ~o);
}

// ---- prep: cnorm (exact fp32) + zero loss/counter ----
__global__ __launch_bounds__(256) void prep_norm(const float* __restrict__ C,
                                                 float* __restrict__ cnorm,
                                                 float* __restrict__ out,
                                                 int* __restrict__ counter) {
    int j = blockIdx.x * 256 + threadIdx.x;
    if (j == 0) { out[OUT_ELEMS] = 0.f; *counter = 0; }
    if (j >= NCODE_PAD) return;
    if (j >= NCODE) { cnorm[j] = 3.0e38f; return; }
    float s = 0.f;
#pragma unroll 8
    for (int d = 0; d < EMBED; ++d) {
        float v = C[d * NCODE + j];
        s = fmaf(v, v, s);
    }
    cnorm[j] = s;
}

// ---- prep: codes -> split-bf16 A-streams (swizzled) + CT fp32 [n][k] ----
// layout per chunk: [mb][ks][kh][row32][8]
__global__ __launch_bounds__(256) void prep_c4(const float* __restrict__ C,
                                               ushort_t* __restrict__ Ah,
                                               ushort_t* __restrict__ Al,
                                               float* __restrict__ CT) {
    int o = blockIdx.x * 256 + threadIdx.x;   // 163840 threads
    int n  = o % NCODE_PAD;
    int kg = o / NCODE_PAD;                   // 0..15
    int split = n / SPLIT_CODES;
    int rem   = n % SPLIT_CODES;
    int chunk = rem >> 6;
    int mb    = (rem >> 5) & 1;
    int row   = rem & 31;
    int ks = kg >> 1, kh = kg & 1;
    size_t eoff = (size_t)(split * NCHUNK + chunk) * CHUNK_ELEMS
                + (size_t)(mb * 4096 + (ks * 2 + kh) * 256 + row * 8);
    int k0 = kg * 8;
    float f[8];
#pragma unroll
    for (int j = 0; j < 8; ++j)
        f[j] = (n < NCODE) ? C[(size_t)(k0 + j) * NCODE + n] : 0.f;
    *(float4*)(CT + (size_t)n * EMBED + k0)     = make_float4(f[0], f[1], f[2], f[3]);
    *(float4*)(CT + (size_t)n * EMBED + k0 + 4) = make_float4(f[4], f[5], f[6], f[7]);
    s16x8 vh, vl;
#pragma unroll
    for (int j = 0; j < 8; ++j) {
        unsigned short h = f2bf(f[j]);
        vh[j] = (short)h;
        vl[j] = (short)f2bf(f[j] - bf2f(h));
    }
    *(s16x8*)(Ah + eoff) = vh;
    *(s16x8*)(Al + eoff) = vl;
}

// ---- main: persistent-X (B, -2x split h+l), codes (A, split h+l) LDS dbuf ----
// dist = cnorm (exact, epilogue) + [AhBh + AhBl + AlBh]. Argmin per-lane.
// R11: mb processed SEQUENTIALLY -> only 2 live f32x16 accs (32 VGPR) to
// eliminate the R10 scratch spill (WRITE_SIZE 38.9 MB -> expect ~1.6 MB).
__global__ __launch_bounds__(256, 2) void vq7(const float* __restrict__ X,
                                              const ushort_t* __restrict__ Ah,
                                              const ushort_t* __restrict__ Al,
                                              const float* __restrict__ cnorm,
                                              u64* __restrict__ candKey,
                                              unsigned* __restrict__ cand2) {
    __shared__ ushort_t Bs[2 * 2 * CHUNK_ELEMS];   // 64 KB: buf{0,1} x {h,l}
    const int t    = threadIdx.x;
    const int lane = t & 63;
    const int wave = t >> 6;
    const int ln   = lane & 31;
    const int kh   = lane >> 5;
    const int split = blockIdx.y;
    const int m0    = blockIdx.x * 256;

    // ---- persistent B frags: (-2x) RNE-split hi+lo (128 VGPR) ----
    s16x8 bh[2][8], bl[2][8];
#pragma unroll
    for (int g = 0; g < 2; ++g) {
        int m = m0 + wave * 64 + g * 32 + ln;
#pragma unroll
        for (int ks = 0; ks < 8; ++ks) {
            const float* src = X + (size_t)m * EMBED + ks * 16 + kh * 8;
            float4 f0 = *(const float4*)src;
            float4 f1 = *(const float4*)(src + 4);
            float f[8] = {f0.x, f0.y, f0.z, f0.w, f1.x, f1.y, f1.z, f1.w};
            s16x8 vh, vl;
#pragma unroll
            for (int j = 0; j < 8; ++j) {
                float v = -2.f * f[j];
                unsigned short h = f2bf(v);
                vh[j] = (short)h;
                vl[j] = (short)f2bf(v - bf2f(h));
            }
            bh[g][ks] = vh;
            bl[g][ks] = vl;
        }
    }

    float v1[2] = {3.4e38f, 3.4e38f}, v2[2] = {3.4e38f, 3.4e38f};
    int   j1[2] = {0, 0};

    auto ldsw = (__attribute__((address_space(3))) ushort_t*)Bs;
    const int woff = wave * 2048;              // 4 KB slice per wave per {h,l}
    const size_t chbase = (size_t)(split * NCHUNK) * CHUNK_ELEMS;

    // ---- stage chunk 0 into buf 0 (h and l) ----
    {
        const ushort_t* sh = Ah + chbase + woff + lane * 8;
        const ushort_t* sl = Al + chbase + woff + lane * 8;
#pragma unroll
        for (int i = 0; i < 4; ++i) {
            __builtin_amdgcn_global_load_lds(
                (const __attribute__((address_space(1))) void*)(sh + i * 512),
                (__attribute__((address_space(3))) void*)(ldsw + woff + i * 512),
                16, 0, 0);
            __builtin_amdgcn_global_load_lds(
                (const __attribute__((address_space(1))) void*)(sl + i * 512),
                (__attribute__((address_space(3))) void*)(ldsw + CHUNK_ELEMS + woff + i * 512),
                16, 0, 0);
        }
    }
    __syncthreads();

    for (int c = 0; c < NCHUNK; ++c) {
        const int b = c & 1;
        // ---- prefetch chunk c+1 into the other buffer (async) ----
        if (c + 1 < NCHUNK) {
            const size_t sb = chbase + (size_t)(c + 1) * CHUNK_ELEMS;
            const ushort_t* sh = Ah + sb + woff + lane * 8;
            const ushort_t* sl = Al + sb + woff + lane * 8;
            const int db = (1 - b) * 2 * CHUNK_ELEMS + woff;
#pragma unroll
            for (int i = 0; i < 4; ++i) {
                __builtin_amdgcn_global_load_lds(
                    (const __attribute__((address_space(1))) void*)(sh + i * 512),
                    (__attribute__((address_space(3))) void*)(ldsw + db + i * 512),
                    16, 0, 0);
                __builtin_amdgcn_global_load_lds(
                    (const __attribute__((address_space(1))) void*)(sl + i * 512),
                    (__attribute__((address_space(3))) void*)(ldsw + db + CHUNK_ELEMS + i * 512),
                    16, 0, 0);
            }
        }

        const int bb = b * 2 * CHUNK_ELEMS;
        const int cbase = split * SPLIT_CODES + c * 64 + 4 * kh;

        // ---- mb sequential: 2 live accs, per-mb epilogue ----
#pragma unroll
        for (int mb = 0; mb < 2; ++mb) {
            f32x16 acc0 = {0,0,0,0,0,0,0,0,0,0,0,0,0,0,0,0};
            f32x16 acc1 = {0,0,0,0,0,0,0,0,0,0,0,0,0,0,0,0};
#pragma unroll
            for (int ks = 0; ks < 8; ++ks) {
                const int fo = bb + mb * 4096 + (ks * 2 + kh) * 256 + ln * 8;
                s16x8 a_h = *(const s16x8*)&Bs[fo];
                s16x8 a_l = *(const s16x8*)&Bs[CHUNK_ELEMS + fo];
                acc0 = __builtin_amdgcn_mfma_f32_32x32x16_bf16(a_h, bh[0][ks], acc0, 0, 0, 0);
                acc1 = __builtin_amdgcn_mfma_f32_32x32x16_bf16(a_h, bh[1][ks], acc1, 0, 0, 0);
                acc0 = __builtin_amdgcn_mfma_f32_32x32x16_bf16(a_h, bl[0][ks], acc0, 0, 0, 0);
                acc1 = __builtin_amdgcn_mfma_f32_32x32x16_bf16(a_h, bl[1][ks], acc1, 0, 0, 0);
                acc0 = __builtin_amdgcn_mfma_f32_32x32x16_bf16(a_l, bh[0][ks], acc0, 0, 0, 0);
                acc1 = __builtin_amdgcn_mfma_f32_32x32x16_bf16(a_l, bh[1][ks], acc1, 0, 0, 0);
            }
            // epilogue for this mb: d = acc + exact cnorm; per-lane top-2
#pragma unroll
            for (int r = 0; r < 16; ++r) {
                const int code = cbase + mb * 32 + ((r & 3) + 8 * (r >> 2));
                const float cn = cnorm[code];     // 256-B window, L1-hot
                float d;
                d = acc0[r] + cn;
                if (d < v1[0]) { v2[0] = v1[0]; v1[0] = d; j1[0] = code; }
                else           { v2[0] = fminf(v2[0], d); }
                d = acc1[r] + cn;
                if (d < v1[1]) { v2[1] = v1[1]; v1[1] = d; j1[1] = code; }
                else           { v2[1] = fminf(v2[1], d); }
            }
        }
        __syncthreads();   // buf b reads done; prefetch into 1-b drained
    }

    // merge lane^32 (same sample, other code-subset), emit per-split top-2
#pragma unroll
    for (int g = 0; g < 2; ++g) {
        float ov1 = __shfl_xor(v1[g], 32, 64);
        int   oj1 = __shfl_xor(j1[g], 32, 64);
        float ov2 = __shfl_xor(v2[g], 32, 64);
        float hi = fmaxf(v1[g], ov1);
        v2[g] = fminf(fminf(v2[g], ov2), hi);
        if (ov1 < v1[g] || (ov1 == v1[g] && oj1 < j1[g])) { v1[g] = ov1; j1[g] = oj1; }
        if (kh == 0) {
            int m = m0 + wave * 64 + g * 32 + ln;
            candKey[(size_t)m * NSPLIT + split] =
                ((u64)ordf(v1[g]) << 32) | (unsigned)j1[g];
            cand2[(size_t)m * NSPLIT + split] = ordf(v2[g]);
        }
    }
}

// ---- fused finalize + output: merge 8 candidates, flag near-ties, gather, loss ----
__global__ __launch_bounds__(256) void outfin_k(const float* __restrict__ X,
                                                const float* __restrict__ CT,
                                                const u64* __restrict__ candKey,
                                                const unsigned* __restrict__ cand2,
                                                int* __restrict__ idxf,
                                                int* __restrict__ rlist,
                                                int* __restrict__ counter,
                                                u64* __restrict__ wsBest,
                                                float* __restrict__ out) {
    __shared__ float red[4];
    const int t = threadIdx.x;
    const int m = blockIdx.x * 8 + (t >> 5);
    const int l = t & 31;

    int code = 0;
    if (l == 0) {
        u64 best = 0xffffffffffffffffull;
        float v2 = 3.4e38f;
#pragma unroll
        for (int s = 0; s < NSPLIT; ++s) {
            u64 k = candKey[(size_t)m * NSPLIT + s];
            unsigned o2 = cand2[(size_t)m * NSPLIT + s];
            if (k < best) {
                if (best != 0xffffffffffffffffull)
                    v2 = fminf(v2, unordf((unsigned)(best >> 32)));
                best = k;
                v2 = fminf(v2, unordf(o2));
            } else {
                v2 = fminf(v2, unordf((unsigned)(k >> 32)));
            }
        }
        code = (int)(unsigned)(best & 0xffffffffu);
        idxf[m] = code;
        float v1 = unordf((unsigned)(best >> 32));
        if (v2 - v1 <= TAU) {
            rlist[atomicAdd(counter, 1)] = m;
            wsBest[m] = 0xffffffffffffffffull;   // init for rescue atomicMin
        }
    }
    code = __shfl(code, 0, 32);

    float4 q = *(const float4*)(CT + (size_t)code * EMBED + l * 4);
    float4 x = *(const float4*)(X + (size_t)m * EMBED + l * 4);
    *(float4*)(out + (size_t)m * EMBED + l * 4) = q;
    float dx = q.x - x.x, dy = q.y - x.y, dz = q.z - x.z, dw = q.w - x.w;
    float lsum = dx * dx + dy * dy + dz * dz + dw * dw;
#pragma unroll
    for (int off = 1; off < 64; off <<= 1) lsum += __shfl_xor(lsum, off, 64);
    if ((t & 63) == 0) red[t >> 6] = lsum;
    __syncthreads();
    if (t == 0)
        atomicAdd(out + OUT_ELEMS,
                  (red[0] + red[1] + red[2] + red[3]) * (1.25f / (float)OUT_ELEMS));
}

// ---- rescue: exact fp32 argmin; work unit = (flagged sample, 625-code seg) ----
// 8 row-slots x 4-row ILP = 32 rows in flight per block iteration (20 iters).
__global__ __launch_bounds__(256) void rescue_seg(const float* __restrict__ X,
                                                  const float* __restrict__ CT,
                                                  const float* __restrict__ cnorm,
                                                  const int* __restrict__ rlist,
                                                  const int* __restrict__ counter,
                                                  u64* __restrict__ wsBest) {
    __shared__ float xs[EMBED];
    __shared__ u64 wk[4];
    const int t = threadIdx.x;
    const int lane = t & 63;
    const int wave = t >> 6;
    const int hw = t & 31;       // lane within half-wave (dims hw*4..hw*4+3)
    const int slot = t >> 5;     // 0..7 row-slot
    const int cnt = *counter;
    const int nw = cnt * NSEG;

    for (int w = blockIdx.x; w < nw; w += gridDim.x) {
        const int s = w >> 4, seg = w & 15;
        const int m = rlist[s];
        __syncthreads();   // previous iteration's xs/wk reads complete
        if (t < 32) {
            float4 v = *(const float4*)(X + (size_t)m * EMBED + t * 4);
            xs[t * 4 + 0] = v.x; xs[t * 4 + 1] = v.y;
            xs[t * 4 + 2] = v.z; xs[t * 4 + 3] = v.w;
        }
        __syncthreads();
        const float x0 = xs[hw * 4 + 0], x1 = xs[hw * 4 + 1];
        const float x2 = xs[hw * 4 + 2], x3 = xs[hw * 4 + 3];
        const int base = seg * 625;          // 16*625 = 10000 exactly
        const int jend = base + 625;
        u64 bk = 0xffffffffffffffffull;
        for (int it = 0; it < 20; ++it) {
            const int r0 = base + it * 32 + slot * 4;
            float4 c0, c1, c2, c3;
            bool ok0 = (r0 + 0 < jend), ok1 = (r0 + 1 < jend);
            bool ok2 = (r0 + 2 < jend), ok3 = (r0 + 3 < jend);
            c0 = ok0 ? *(const float4*)(CT + (size_t)(r0 + 0) * EMBED + hw * 4) : make_float4(0, 0, 0, 0);
            c1 = ok1 ? *(const float4*)(CT + (size_t)(r0 + 1) * EMBED + hw * 4) : make_float4(0, 0, 0, 0);
            c2 = ok2 ? *(const float4*)(CT + (size_t)(r0 + 2) * EMBED + hw * 4) : make_float4(0, 0, 0, 0);
            c3 = ok3 ? *(const float4*)(CT + (size_t)(r0 + 3) * EMBED + hw * 4) : make_float4(0, 0, 0, 0);
            float p0 = x0 * c0.x, p1 = x0 * c1.x, p2 = x0 * c2.x, p3 = x0 * c3.x;
            p0 = fmaf(x1, c0.y, p0); p1 = fmaf(x1, c1.y, p1);
            p2 = fmaf(x1, c2.y, p2); p3 = fmaf(x1, c3.y, p3);
            p0 = fmaf(x2, c0.z, p0); p1 = fmaf(x2, c1.z, p1);
            p2 = fmaf(x2, c2.z, p2); p3 = fmaf(x2, c3.z, p3);
            p0 = fmaf(x3, c0.w, p0); p1 = fmaf(x3, c1.w, p1);
            p2 = fmaf(x3, c2.w, p2); p3 = fmaf(x3, c3.w, p3);
#pragma unroll
            for (int off = 1; off < 32; off <<= 1) {   // 4 interleaved chains
                p0 += __shfl_xor(p0, off, 32);
                p1 += __shfl_xor(p1, off, 32);
                p2 += __shfl_xor(p2, off, 32);
                p3 += __shfl_xor(p3, off, 32);
            }
            if (hw == 0) {
                if (ok0) { u64 k = ((u64)ordf(fmaf(-2.f, p0, cnorm[r0 + 0])) << 32) | (unsigned)(r0 + 0); if (k < bk) bk = k; }
                if (ok1) { u64 k = ((u64)ordf(fmaf(-2.f, p1, cnorm[r0 + 1])) << 32) | (unsigned)(r0 + 1); if (k < bk) bk = k; }
                if (ok2) { u64 k = ((u64)ordf(fmaf(-2.f, p2, cnorm[r0 + 2])) << 32) | (unsigned)(r0 + 2); if (k < bk) bk = k; }
                if (ok3) { u64 k = ((u64)ordf(fmaf(-2.f, p3, cnorm[r0 + 3])) << 32) | (unsigned)(r0 + 3); if (k < bk) bk = k; }
            }
        }
#pragma unroll
        for (int off = 1; off < 64; off <<= 1) {
            u64 o = __shfl_xor(bk, off, 64);
            if (o < bk) bk = o;
        }
        if (lane == 0) wk[wave] = bk;
        __syncthreads();
        if (t == 0) {
            u64 b = wk[0];
            if (wk[1] < b) b = wk[1];
            if (wk[2] < b) b = wk[2];
            if (wk[3] < b) b = wk[3];
            atomicMin(&wsBest[m], b);
        }
    }
}

// ---- patch: apply argmin flips found by rescue ----
__global__ __launch_bounds__(256) void patch_k(const float* __restrict__ X,
                                               const float* __restrict__ CT,
                                               const int* __restrict__ rlist,
                                               const int* __restrict__ counter,
                                               const u64* __restrict__ wsBest,
                                               const int* __restrict__ idxf,
                                               float* __restrict__ out) {
    const int t = threadIdx.x;
    const int l = t & 31, sl = t >> 5;
    const int cnt = *counter;
    for (int s = blockIdx.x * 8 + sl; s < cnt; s += gridDim.x * 8) {
        int m = rlist[s];
        u64 key = wsBest[m];
        int jn = (int)(unsigned)(key & 0xffffffffu);
        int jo = idxf[m];
        if (jn == jo) continue;   // uniform within 32-lane group
        float4 qn = *(const float4*)(CT + (size_t)jn * EMBED + l * 4);
        float4 qo = *(const float4*)(CT + (size_t)jo * EMBED + l * 4);
        float4 x  = *(const float4*)(X + (size_t)m * EMBED + l * 4);
        *(float4*)(out + (size_t)m * EMBED + l * 4) = qn;
        float dn = (qn.x - x.x) * (qn.x - x.x) + (qn.y - x.y) * (qn.y - x.y)
                 + (qn.z - x.z) * (qn.z - x.z) + (qn.w - x.w) * (qn.w - x.w);
        float dp = (qo.x - x.x) * (qo.x - x.x) + (qo.y - x.y) * (qo.y - x.y)
                 + (qo.z - x.z) * (qo.z - x.z) + (qo.w - x.w) * (qo.w - x.w);
        float delta = dn - dp;
#pragma unroll
        for (int off = 1; off < 32; off <<= 1) delta += __shfl_xor(delta, off, 32);
        if (l == 0)
            atomicAdd(out + OUT_ELEMS, delta * (1.25f / (float)OUT_ELEMS));
    }
}

extern "C" void kernel_launch(void* const* d_in, const int* in_sizes, int n_in,
                              void* d_out, int out_size, void* d_ws, size_t ws_size,
                              hipStream_t stream) {
    const float* X = (const float*)d_in[0];   // (16384,128) fp32
    const float* C = (const float*)d_in[1];   // (128,10000) fp32
    float* out = (float*)d_out;
    char* ws = (char*)d_ws;

    ushort_t* Ah = (ushort_t*)(ws + OFF_AH);
    ushort_t* Al = (ushort_t*)(ws + OFF_AL);
    float* CT    = (float*)(ws + OFF_CT);
    float* cnorm = (float*)(ws + OFF_CN);
    u64* candKey = (u64*)(ws + OFF_KEY);
    unsigned* cand2 = (unsigned*)(ws + OFF_C2);
    int* idxf    = (int*)(ws + OFF_IDX);
    int* rlist   = (int*)(ws + OFF_RL);
    int* counter = (int*)(ws + OFF_CNT);
    u64* wsBest  = (u64*)(ws + OFF_BEST);

    prep_norm<<<NCODE_PAD / 256, 256, 0, stream>>>(C, cnorm, out, counter);
    prep_c4<<<(NCODE_PAD * 16) / 256, 256, 0, stream>>>(C, Ah, Al, CT);
    vq7<<<dim3(NSAMP / 256, NSPLIT), 256, 0, stream>>>(X, Ah, Al, cnorm, candKey, cand2);
    outfin_k<<<NSAMP / 8, 256, 0, stream>>>(X, CT, candKey, cand2, idxf, rlist, counter, wsBest, out);
    rescue_seg<<<1024, 256, 0, stream>>>(X, CT, cnorm, rlist, counter, wsBest);
    patch_k<<<64, 256, 0, stream>>>(X, CT, rlist, counter, wsBest, idxf, out);
}